// Round 3
// baseline (316.091 us; speedup 1.0000x reference)
//
#include <hip/hip_runtime.h>
#include <math.h>

#define KK 256
#define NN 65536
#define WW 48    // scan lookback window; decay<=e^-1 -> tail error ~e^-48
#define TA 128   // t-tile per scan block (512 blocks)
#define TG 64    // t-tile per gemm block (1024 blocks)
#define NTILE (NN / TA)  // 512

typedef __bf16 bf16x8 __attribute__((ext_vector_type(8)));
typedef float f32x4 __attribute__((ext_vector_type(4)));

// ---------------------------------------------------------------------------
// Kernel 1 (scan): block c covers t in [c*TA, c*TA+TA).
//   Thread k: WW-step window preamble, then scan; writes ST[t][k] (bf16,
//   coalesced: lane=k adjacent) and per-tile row sum partial[c*KK+k].
//   S[k,t] = Beta[k]*G[k,t], G[k,t] = decay_k*(G[k,t-1]+obs[k,t-1]).
// ---------------------------------------------------------------------------
__global__ __launch_bounds__(256) void scan_kernel(const float* __restrict__ obs,
                                                   const float* __restrict__ Beta,
                                                   __bf16* __restrict__ ST,
                                                   float* __restrict__ partial) {
  const int c = blockIdx.x;
  const int k = threadIdx.x;
  const int t0 = c * TA;
  const float beta = Beta[k];
  const float decay = __expf(-beta);
  const float* row = obs + (size_t)k * NN;

  float g = 0.f;  // ~ G[k, t0-WW]; tail < e^-48
  if (t0 > 0) {
    const float4* p = (const float4*)(row + t0 - WW);
#pragma unroll
    for (int i = 0; i < WW / 4; ++i) {
      float4 v = p[i];
      g = decay * (g + v.x);
      g = decay * (g + v.y);
      g = decay * (g + v.z);
      g = decay * (g + v.w);
    }
  }

  __bf16* st = ST + (size_t)t0 * KK + k;
  st[0] = (__bf16)(beta * g);  // S[t0] (t0==0 -> exactly 0; col 0 overridden in gemm)

  float rsum = 0.f;
  const float4* q = (const float4*)(row + t0);
#pragma unroll 4
  for (int i = 0; i < TA / 4 - 1; ++i) {  // produce S[t0+4i+1 .. t0+4i+4]
    float4 v = q[i];
    rsum += (v.x + v.y) + (v.z + v.w);
    g = decay * (g + v.x); st[(size_t)(4 * i + 1) * KK] = (__bf16)(beta * g);
    g = decay * (g + v.y); st[(size_t)(4 * i + 2) * KK] = (__bf16)(beta * g);
    g = decay * (g + v.z); st[(size_t)(4 * i + 3) * KK] = (__bf16)(beta * g);
    g = decay * (g + v.w); st[(size_t)(4 * i + 4) * KK] = (__bf16)(beta * g);
  }
  {  // last float4 of tile: S[TA-3..TA-1]; .w only feeds the row sum
    float4 v = q[TA / 4 - 1];
    rsum += (v.x + v.y) + (v.z + v.w);
    g = decay * (g + v.x); st[(size_t)(TA - 3) * KK] = (__bf16)(beta * g);
    g = decay * (g + v.y); st[(size_t)(TA - 2) * KK] = (__bf16)(beta * g);
    g = decay * (g + v.z); st[(size_t)(TA - 1) * KK] = (__bf16)(beta * g);
  }
  partial[c * KK + k] = rsum;  // coalesced
}

// ---------------------------------------------------------------------------
// Kernel 2 (prep): finalize mu0 from NTILE partials/row, Alpha -> bf16,
//   zero loglik accumulator. Block j handles row j.
// ---------------------------------------------------------------------------
__global__ __launch_bounds__(256) void prep_kernel(const float* __restrict__ Alpha,
                                                   const float* __restrict__ partial,
                                                   float* __restrict__ mu0,
                                                   __bf16* __restrict__ AlphaB,
                                                   float* __restrict__ out) {
  const int j = blockIdx.x;
  const int tid = threadIdx.x;
  AlphaB[(size_t)j * KK + tid] = (__bf16)Alpha[(size_t)j * KK + tid];
  float s = partial[(size_t)tid * KK + j] + partial[(size_t)(tid + 256) * KK + j];
  __shared__ float red[256];
  red[tid] = s;
  __syncthreads();
  for (int off = 128; off > 0; off >>= 1) {
    if (tid < off) red[tid] += red[tid + off];
    __syncthreads();
  }
  if (tid == 0) {
    mu0[j] = red[0] * (1.0f / NN) * 0.1f + 0.01f;
    if (j == 0) out[0] = 0.f;  // d_out is poisoned; zero the accumulator
  }
}

// ---------------------------------------------------------------------------
// Kernel 3 (gemm): no LDS, no barriers. Block b: t in [b*TG, b*TG+TG),
//   wave w: j in [64w, 64w+64). MFMA 16x16x32 bf16; B-frags read straight
//   from ST (t-major: k-octets are 16B-contiguous, lquad groups give 64B
//   line utilization). Epilogue: softplus, lams0/lams1, loglik partial.
// ---------------------------------------------------------------------------
__global__ __launch_bounds__(256, 4) void gemm_kernel(const float* __restrict__ obs,
                                                      const float* __restrict__ mu0,
                                                      const __bf16* __restrict__ AlphaB,
                                                      const __bf16* __restrict__ ST,
                                                      float* __restrict__ out) {
  const int tid = threadIdx.x;
  const int t0 = blockIdx.x * TG;
  const int wave = tid >> 6;
  const int lane = tid & 63;
  const int lquad = lane >> 4;  // k-octet in frag / j-sub in C
  const int l16 = lane & 15;

  f32x4 acc[4][4];  // [jsub][tsub]
#pragma unroll
  for (int a = 0; a < 4; ++a)
#pragma unroll
    for (int b = 0; b < 4; ++b) acc[a][b] = (f32x4){0.f, 0.f, 0.f, 0.f};

  const __bf16* Abase = AlphaB + (size_t)(wave * 64 + l16) * KK + lquad * 8;
  const __bf16* Bbase = ST + (size_t)(t0 + l16) * KK + lquad * 8;
#pragma unroll
  for (int k0 = 0; k0 < KK; k0 += 32) {
    bf16x8 afrag[4], bfrag[4];
#pragma unroll
    for (int js = 0; js < 4; ++js)
      afrag[js] = *(const bf16x8*)(Abase + (size_t)js * 16 * KK + k0);
#pragma unroll
    for (int ts = 0; ts < 4; ++ts)
      bfrag[ts] = *(const bf16x8*)(Bbase + (size_t)ts * 16 * KK + k0);
#pragma unroll
    for (int js = 0; js < 4; ++js)
#pragma unroll
      for (int ts = 0; ts < 4; ++ts)
        acc[js][ts] = __builtin_amdgcn_mfma_f32_16x16x32_bf16(
            afrag[js], bfrag[ts], acc[js][ts], 0, 0, 0);
  }

  // ---- epilogue ----
  float partial = 0.f;
  float* lams0 = out + 1;
  float* lams1 = out + 1 + (size_t)KK * NN;
#pragma unroll
  for (int js = 0; js < 4; ++js) {
#pragma unroll
    for (int r = 0; r < 4; ++r) {
      const int j = wave * 64 + js * 16 + lquad * 4 + r;  // D-layout row
      const float m = mu0[j];
      const size_t rowoff = (size_t)j * NN + t0 + l16;
#pragma unroll
      for (int ts = 0; ts < 4; ++ts) {
        float v = acc[js][ts][r];                    // v >= 0 always
        float lam = v + __logf(1.f + __expf(-v));    // stable softplus
        if (t0 + ts * 16 + l16 == 0) lam = 0.f;      // lams1[:,0] = 0
        lams1[rowoff + ts * 16] = lam;
        lams0[rowoff + ts * 16] = m;
        const float o = obs[rowoff + ts * 16];
        partial += o * __logf(m + lam + 1e-5f) - m - lam;
      }
    }
  }

#pragma unroll
  for (int off = 32; off > 0; off >>= 1)
    partial += __shfl_down(partial, off, 64);
  if (lane == 0) atomicAdd(out, partial);
}

// ---------------------------------------------------------------------------
extern "C" void kernel_launch(void* const* d_in, const int* in_sizes, int n_in,
                              void* d_out, int out_size, void* d_ws, size_t ws_size,
                              hipStream_t stream) {
  const float* obs   = (const float*)d_in[0];
  const float* Beta  = (const float*)d_in[1];
  const float* Alpha = (const float*)d_in[2];
  float* out = (float*)d_out;

  // workspace layout
  float* partial = (float*)d_ws;                    // NTILE*KK = 512 KB
  float* mu0 = partial + NTILE * KK;                // 1 KB
  __bf16* AlphaB = (__bf16*)(mu0 + 256);            // 128 KB
  __bf16* ST = AlphaB + KK * KK;                    // KK*NN bf16 = 32 MB

  hipLaunchKernelGGL(scan_kernel, dim3(NTILE), dim3(256), 0, stream,
                     obs, Beta, ST, partial);
  hipLaunchKernelGGL(prep_kernel, dim3(KK), dim3(256), 0, stream,
                     Alpha, partial, mu0, AlphaB, out);
  hipLaunchKernelGGL(gemm_kernel, dim3(NN / TG), dim3(256), 0, stream,
                     obs, mu0, AlphaB, ST, out);
}